// Round 12
// baseline (437.533 us; speedup 1.0000x reference)
//
#include <hip/hip_runtime.h>
#include <cstdint>
#include <cstddef>

typedef _Float16 f16;
typedef _Float16 f16x4 __attribute__((ext_vector_type(4)));
typedef _Float16 f16x8 __attribute__((ext_vector_type(8)));
typedef float    f32x4 __attribute__((ext_vector_type(4)));

#define NB 64
#define NN 262144   // 512*512

__device__ __forceinline__ void gload_lds16(const void* g, void* l) {
    __builtin_amdgcn_global_load_lds(
        (const __attribute__((address_space(1))) void*)g,
        (__attribute__((address_space(3))) void*)l, 16, 0, 0);
}

// cvtX: X_h = f16(X0)
__global__ void k_cvtX(const float* __restrict__ x, f16* __restrict__ xh) {
    size_t i = ((size_t)blockIdx.x * 256 + threadIdx.x) * 8;
    float4 v0 = *(const float4*)(x + i);
    float4 v1 = *(const float4*)(x + i + 4);
    f16x8 o;
    o[0] = (f16)v0.x; o[1] = (f16)v0.y; o[2] = (f16)v0.z; o[3] = (f16)v0.w;
    o[4] = (f16)v1.x; o[5] = (f16)v1.y; o[6] = (f16)v1.z; o[7] = (f16)v1.w;
    *(f16x8*)(xh + i) = o;
}

// prep: [0,4096): A_raw transpose tiles + colsum partials (adj read once);
//       [4096,4288): transW.
__global__ __launch_bounds__(256)
void k_prep(const float* __restrict__ adj, f16* __restrict__ A_raw,
            float* __restrict__ part,
            const float* __restrict__ W1, const float* __restrict__ W2,
            const float* __restrict__ W3, f16* __restrict__ Wt) {
    __shared__ float t[64][68];
    __shared__ float red[4][64];
    const int bid = blockIdx.x, tid = threadIdx.x;
    if (bid < 4096) {
        const int xcd = bid & 7, loc = bid >> 3;
        const int b = xcd * 8 + (loc >> 6);
        const int tile = loc & 63;
        const int i0 = (tile >> 3) * 64, j0 = (tile & 7) * 64;
        const int jt = tile & 7;
        const float* ab = adj + (size_t)b * NN;
        int trow = tid >> 4;
        int tc4  = (tid & 15) * 4;
        #pragma unroll
        for (int s = 0; s < 4; ++s) {
            int rr = trow + s * 16;
            *(f32x4*)&t[rr][tc4] = *(const f32x4*)&ab[(size_t)(j0 + rr) * 512 + i0 + tc4];
        }
        __syncthreads();
        {
            int c = tid & 63, g = tid >> 6;
            float sg = 0.f;
            #pragma unroll
            for (int s = 0; s < 16; ++s) sg += t[g * 16 + s][c];
            red[g][c] = sg;
        }
        f16* Ab = A_raw + (size_t)b * NN;
        int jq = (tid & 15) * 4;
        int ib = tid >> 4;
        #pragma unroll
        for (int s = 0; s < 4; ++s) {
            int ii = ib + s * 16;
            f16x4 o;
            #pragma unroll
            for (int q = 0; q < 4; ++q) o[q] = (f16)t[jq + q][ii];
            *(f16x4*)&Ab[(size_t)(i0 + ii) * 512 + j0 + jq] = o;
        }
        __syncthreads();
        if (tid < 64)
            part[((size_t)b * 8 + jt) * 512 + i0 + tid] =
                red[0][tid] + red[1][tid] + red[2][tid] + red[3][tid];
    } else {
        int cb = bid - 4096;
        int z = cb >> 6, rem = cb & 63;
        const float* W = z == 0 ? W1 : (z == 1 ? W2 : W3);
        f16* out = Wt + (size_t)z * NN;
        int k0 = (rem >> 3) * 64, d0 = (rem & 7) * 64;
        int c = tid & 63, r4 = tid >> 6;
        #pragma unroll
        for (int s = 0; s < 16; ++s) {
            int rr = r4 + s * 4;
            t[rr][c] = W[(size_t)(k0 + rr) * 512 + d0 + c];
        }
        __syncthreads();
        int kq = (tid & 15) * 4;
        int db = tid >> 4;
        #pragma unroll
        for (int s = 0; s < 4; ++s) {
            int dd = db + s * 16;
            f16x4 o;
            #pragma unroll
            for (int q = 0; q < 4; ++q)
                o[q] = (f16)(64.f * t[kq + q][dd]);
            *(f16x4*)&out[(size_t)(d0 + dd) * 512 + k0 + kq] = o;
        }
    }
}

// r[b][n] = rsqrt(colsum), 0 -> 0 ; block 0 also zeroes the sync counters
__global__ void k_fin(const float* __restrict__ part, float* __restrict__ r,
                      uint32_t* __restrict__ syncb) {
    int idx = blockIdx.x * 256 + threadIdx.x;
    if (blockIdx.x == 0) {
        syncb[threadIdx.x] = 0;
        syncb[threadIdx.x + 256] = 0;
    }
    int b = idx >> 9, n = idx & 511;
    const float* p = part + (size_t)b * 8 * 512 + n;
    float s = 0.f;
    #pragma unroll
    for (int jt = 0; jt < 8; ++jt) s += p[jt * 512];
    r[idx] = (s > 0.f) ? rsqrtf(s) : 0.f;
}

// One GEMM stage for a 128x128 tile. C[m][n]=sum_k P[m][k]*Qt[n][k], out Ct[n][m].
template<bool BIAS, bool RELU, bool OUTF32, bool RM, bool RN>
__device__ __forceinline__ void gemm_body(
    f16* PL, f16* QL,
    const f16* __restrict__ Pb, const f16* __restrict__ Qb, void* __restrict__ Cb,
    const float* __restrict__ bias, const float* __restrict__ rs,
    float iscale, float oscale, int m0, int n0) {
    const int tid  = threadIdx.x;
    const int lane = tid & 63;
    const int wid  = tid >> 6;
    const int wm = wid >> 1, wn = wid & 1;
    const int srow = tid >> 3;
    const int sswz = (tid & 7) ^ (srow & 7);
    const int fr = lane & 15, fs = lane >> 4, fx = fr & 7;

    auto stage = [&](const f16* __restrict__ Gb, int row0, f16* lds, int k0) {
        #pragma unroll
        for (int r = 0; r < 4; ++r) {
            const f16* src = Gb + (size_t)(row0 + r * 32 + srow) * 512 + k0 + sswz * 8;
            gload_lds16(src, lds + r * 2048 + tid * 8);
        }
    };

    f32x4 acc[4][4] = {};
    stage(Pb, m0, PL, 0);
    stage(Qb, n0, QL, 0);

    for (int t = 0; t < 8; ++t) {
        const int nb = t & 1;
        if (t < 7) {
            stage(Pb, m0, PL + (nb ^ 1) * 8192, (t + 1) * 64);
            stage(Qb, n0, QL + (nb ^ 1) * 8192, (t + 1) * 64);
            asm volatile("s_waitcnt vmcnt(8)" ::: "memory");
        } else {
            asm volatile("s_waitcnt vmcnt(0)" ::: "memory");
        }
        __builtin_amdgcn_s_barrier();

        const f16* Pl = PL + nb * 8192;
        const f16* Ql = QL + nb * 8192;
        #pragma unroll
        for (int krep = 0; krep < 2; ++krep) {
            const int sp = ((fs + krep * 4) ^ fx) * 8;
            f16x8 af[4], bf[4];
            #pragma unroll
            for (int mi = 0; mi < 4; ++mi)
                af[mi] = *(const f16x8*)&Pl[(wm * 64 + mi * 16 + fr) * 64 + sp];
            #pragma unroll
            for (int ni = 0; ni < 4; ++ni)
                bf[ni] = *(const f16x8*)&Ql[(wn * 64 + ni * 16 + fr) * 64 + sp];
            __builtin_amdgcn_s_setprio(1);
            #pragma unroll
            for (int mi = 0; mi < 4; ++mi)
                #pragma unroll
                for (int ni = 0; ni < 4; ++ni)
                    acc[mi][ni] = __builtin_amdgcn_mfma_f32_16x16x32_f16(
                        af[mi], bf[ni], acc[mi][ni], 0, 0, 0);
            __builtin_amdgcn_s_setprio(0);
        }
        asm volatile("s_waitcnt lgkmcnt(0)" ::: "memory");
        __builtin_amdgcn_sched_barrier(0);
        __builtin_amdgcn_s_barrier();
    }

    const int cmb = (lane >> 4) * 4;
    f32x4 rm4[4];
    float rn1[4];
    if (RM) {
        #pragma unroll
        for (int mi = 0; mi < 4; ++mi)
            rm4[mi] = *(const f32x4*)&rs[m0 + wm * 64 + mi * 16 + cmb];
    }
    if (RN) {
        #pragma unroll
        for (int ni = 0; ni < 4; ++ni)
            rn1[ni] = rs[n0 + wn * 64 + ni * 16 + fr];
    }
    #pragma unroll
    for (int mi = 0; mi < 4; ++mi) {
        #pragma unroll
        for (int ni = 0; ni < 4; ++ni) {
            const int n = n0 + wn * 64 + ni * 16 + fr;
            const int m = m0 + wm * 64 + mi * 16 + cmb;
            float v[4];
            #pragma unroll
            for (int q = 0; q < 4; ++q) {
                float x = acc[mi][ni][q] * iscale;
                if (RM) x *= rm4[mi][q];
                if (RN) x *= rn1[ni];
                if (BIAS) x += bias[m + q];
                if (RELU) x = fmaxf(x, 0.f);
                v[q] = x * oscale;
            }
            if (OUTF32) {
                f32x4 o; o[0] = v[0]; o[1] = v[1]; o[2] = v[2]; o[3] = v[3];
                *(f32x4*)&((float*)Cb)[(size_t)n * 512 + m] = o;
            } else {
                f16x4 o; o[0] = (f16)v[0]; o[1] = (f16)v[1]; o[2] = (f16)v[2]; o[3] = (f16)v[3];
                *(f16x4*)&((f16*)Cb)[(size_t)n * 512 + m] = o;
            }
        }
    }
}

// Persistent mega-kernel: 512 WGs (2/CU, all resident). WG -> (batch b, sub 0..7);
// each WG computes tiles sub*2, sub*2+1 for all 6 GEMM stages; per-batch
// device-scope barrier (8 WGs) between stages.
__global__ __launch_bounds__(256, 2)
void k_mega(f16* __restrict__ Xa, f16* __restrict__ S_t,
            const f16* __restrict__ A_raw, const f16* __restrict__ Wt,
            const float* __restrict__ b1, const float* __restrict__ b2,
            const float* __restrict__ b3, const float* __restrict__ rbuf,
            float* __restrict__ outp, uint32_t* __restrict__ syncb) {
    __shared__ __align__(16) f16 Plds[2][8192];
    __shared__ __align__(16) f16 Qlds[2][8192];
    const int wg  = blockIdx.x;
    const int xcd = wg & 7, idx = wg >> 3;
    const int b   = xcd * 8 + (idx >> 3);      // batch -> XCD (locality heuristic only)
    const int sub = idx & 7;
    const int tid = threadIdx.x;

    f16* Xb = Xa + (size_t)b * NN;
    f16* Sb = S_t + (size_t)b * NN;
    const f16* Ab = A_raw + (size_t)b * NN;
    const float* rs = rbuf + (size_t)b * 512;
    float* Ob = outp + (size_t)b * NN;
    uint32_t* sc = syncb + b * 8;
    f16* PL = &Plds[0][0];
    f16* QL = &Qlds[0][0];

    // ledger: Xa = 256^l * X_l ; Wt = 64*W ; S' = c_l*r_j*S_l (c1=256, c2=c3=262144)
    for (int s = 0; s < 6; ++s) {
        #pragma unroll 1
        for (int h = 0; h < 2; ++h) {
            const int tt = sub * 2 + h;
            const int m0 = (tt >> 2) * 128, n0 = (tt & 3) * 128;
            switch (s) {
            case 0: gemm_body<false, false, false, true,  false>(PL, QL, Xb, Wt,          Sb, nullptr, rs, 4.f,           1.f,   m0, n0); break;
            case 1: gemm_body<true,  true,  false, false, true >(PL, QL, Sb, Ab,          Xb, b1,      rs, 1.f/256.f,     256.f, m0, n0); break;
            case 2: gemm_body<false, false, false, true,  false>(PL, QL, Xb, Wt + NN,     Sb, nullptr, rs, 16.f,          1.f,   m0, n0); break;
            case 3: gemm_body<true,  true,  false, false, true >(PL, QL, Sb, Ab,          Xb, b2,      rs, 1.f/262144.f,  256.f, m0, n0); break;
            case 4: gemm_body<false, false, false, true,  false>(PL, QL, Xb, Wt + 2*NN,   Sb, nullptr, rs, 16.f,          1.f,   m0, n0); break;
            case 5: gemm_body<true,  false, true,  false, true >(PL, QL, Sb, Ab,          Ob, b3,      rs, 1.f/262144.f,  1.f,   m0, n0); break;
            }
        }
        if (s < 5) {
            __syncthreads();                           // all WG stores drained (vmcnt0)
            if (tid == 0) {
                __hip_atomic_fetch_add(&sc[s], 1u, __ATOMIC_RELEASE, __HIP_MEMORY_SCOPE_AGENT);
                while (__hip_atomic_load(&sc[s], __ATOMIC_RELAXED, __HIP_MEMORY_SCOPE_AGENT) < 8u)
                    __builtin_amdgcn_s_sleep(8);
            }
            __syncthreads();
            __builtin_amdgcn_fence(__ATOMIC_ACQUIRE, "agent");
        }
    }
}

extern "C" void kernel_launch(void* const* d_in, const int* in_sizes, int n_in,
                              void* d_out, int out_size, void* d_ws, size_t ws_size,
                              hipStream_t stream) {
    const float* X0  = (const float*)d_in[0];
    const float* adj = (const float*)d_in[1];
    const float* W1  = (const float*)d_in[2];
    const float* b1  = (const float*)d_in[3];
    const float* W2  = (const float*)d_in[4];
    const float* b2  = (const float*)d_in[5];
    const float* W3  = (const float*)d_in[6];
    const float* b3  = (const float*)d_in[7];

    uint8_t* ws = (uint8_t*)d_ws;
    float* rbuf = (float*)ws;                              // 128 KiB
    f16* Wt1 = (f16*)(ws + 131072);                        // 3 x 512 KiB
    f16* A_raw = (f16*)(ws + 131072 + (size_t)3 * NN * 2); // 32 MiB (adj^T f16)
    f16* Xa  = A_raw + (size_t)NB * NN;                    // 32 MiB (X / activations)
    f16* S_t = Xa + (size_t)NB * NN;                       // 32 MiB
    uint32_t* syncb = (uint32_t*)(S_t + (size_t)NB * NN);  // 2 KiB sync counters
    float* part = (float*)S_t;   // 1 MiB, aliased (S_t first written by mega, after k_fin)

    k_prep<<<dim3(4288), dim3(256), 0, stream>>>(adj, A_raw, part, W1, W2, W3, Wt1);
    k_cvtX<<<dim3(8192), dim3(256), 0, stream>>>(X0, Xa);
    k_fin <<<dim3(128),  dim3(256), 0, stream>>>(part, rbuf, syncb);

    k_mega<<<dim3(512), dim3(256), 0, stream>>>(Xa, S_t, A_raw, Wt1, b1, b2, b3,
                                                rbuf, (float*)d_out, syncb);
}

// Round 13
// 215.448 us; speedup vs baseline: 2.0308x; 2.0308x over previous
//
#include <hip/hip_runtime.h>
#include <cstdint>
#include <cstddef>

typedef _Float16 f16;
typedef _Float16 f16x4 __attribute__((ext_vector_type(4)));
typedef _Float16 f16x8 __attribute__((ext_vector_type(8)));
typedef float    f32x4 __attribute__((ext_vector_type(4)));

#define NB 64
#define NN 262144   // 512*512

__device__ __forceinline__ void gload_lds16(const void* g, void* l) {
    __builtin_amdgcn_global_load_lds(
        (const __attribute__((address_space(1))) void*)g,
        (__attribute__((address_space(3))) void*)l, 16, 0, 0);
}

// prep: [0,4096): A_raw transpose tiles + colsum partials (adj read once);
//       [4096,4288): transW ; [4288,12480): cvtX.
__global__ __launch_bounds__(256)
void k_prep(const float* __restrict__ adj, f16* __restrict__ A_raw,
            float* __restrict__ part,
            const float* __restrict__ W1, const float* __restrict__ W2,
            const float* __restrict__ W3, f16* __restrict__ Wt,
            const float* __restrict__ X0, f16* __restrict__ Xa) {
    __shared__ float t[64][68];
    __shared__ float red[4][64];
    const int bid = blockIdx.x, tid = threadIdx.x;
    if (bid < 4096) {
        const int xcd = bid & 7, loc = bid >> 3;
        const int b = xcd * 8 + (loc >> 6);
        const int tile = loc & 63;
        const int i0 = (tile >> 3) * 64, j0 = (tile & 7) * 64;
        const int jt = tile & 7;
        const float* ab = adj + (size_t)b * NN;
        int trow = tid >> 4;
        int tc4  = (tid & 15) * 4;
        #pragma unroll
        for (int s = 0; s < 4; ++s) {
            int rr = trow + s * 16;
            *(f32x4*)&t[rr][tc4] = *(const f32x4*)&ab[(size_t)(j0 + rr) * 512 + i0 + tc4];
        }
        __syncthreads();
        {
            int c = tid & 63, g = tid >> 6;
            float sg = 0.f;
            #pragma unroll
            for (int s = 0; s < 16; ++s) sg += t[g * 16 + s][c];
            red[g][c] = sg;
        }
        f16* Ab = A_raw + (size_t)b * NN;
        int jq = (tid & 15) * 4;
        int ib = tid >> 4;
        #pragma unroll
        for (int s = 0; s < 4; ++s) {
            int ii = ib + s * 16;
            f16x4 o;
            #pragma unroll
            for (int q = 0; q < 4; ++q) o[q] = (f16)t[jq + q][ii];
            *(f16x4*)&Ab[(size_t)(i0 + ii) * 512 + j0 + jq] = o;
        }
        __syncthreads();
        if (tid < 64)
            part[((size_t)b * 8 + jt) * 512 + i0 + tid] =
                red[0][tid] + red[1][tid] + red[2][tid] + red[3][tid];
    } else if (bid < 4288) {
        int cb = bid - 4096;
        int z = cb >> 6, rem = cb & 63;
        const float* W = z == 0 ? W1 : (z == 1 ? W2 : W3);
        f16* out = Wt + (size_t)z * NN;
        int k0 = (rem >> 3) * 64, d0 = (rem & 7) * 64;
        int c = tid & 63, r4 = tid >> 6;
        #pragma unroll
        for (int s = 0; s < 16; ++s) {
            int rr = r4 + s * 4;
            t[rr][c] = W[(size_t)(k0 + rr) * 512 + d0 + c];
        }
        __syncthreads();
        int kq = (tid & 15) * 4;
        int db = tid >> 4;
        #pragma unroll
        for (int s = 0; s < 4; ++s) {
            int dd = db + s * 16;
            f16x4 o;
            #pragma unroll
            for (int q = 0; q < 4; ++q)
                o[q] = (f16)(64.f * t[kq + q][dd]);
            *(f16x4*)&out[(size_t)(d0 + dd) * 512 + k0 + kq] = o;
        }
    } else {
        size_t i = ((size_t)(bid - 4288) * 256 + tid) * 8;
        float4 v0 = *(const float4*)(X0 + i);
        float4 v1 = *(const float4*)(X0 + i + 4);
        f16x8 o;
        o[0] = (f16)v0.x; o[1] = (f16)v0.y; o[2] = (f16)v0.z; o[3] = (f16)v0.w;
        o[4] = (f16)v1.x; o[5] = (f16)v1.y; o[6] = (f16)v1.z; o[7] = (f16)v1.w;
        *(f16x8*)(Xa + i) = o;
    }
}

// C[m][n] = sum_k P[m][k]*Qt[n][k]; out Ct[n][m].
// r finished INLINE from colsum partials (512B LDS, overlapped with tile-0 staging).
// RM: x = acc*iscale*r[m]. RN: x = acc*iscale*r[n] (+bias, relu, *oscale).
// 128x128 tile, BK=64, 4 waves, 2 WG/CU, counted-vmcnt(8), XOR swizzle.
template<bool BIAS, bool RELU, bool OUTF32, bool RM, bool RN>
__global__ __launch_bounds__(256, 2)
void gemm_tn_ct(const f16* __restrict__ P, size_t pstr,
                const f16* __restrict__ Qt, size_t qstr,
                void* __restrict__ Cout, size_t cstr,
                const float* __restrict__ bias, const float* __restrict__ part,
                float iscale, float oscale) {
    __shared__ __align__(16) f16 Plds[2][8192];
    __shared__ __align__(16) f16 Qlds[2][8192];
    __shared__ float rs_lds[128];

    const int tid  = threadIdx.x;
    const int lane = tid & 63;
    const int wid  = tid >> 6;
    const int wm   = wid >> 1;
    const int wn   = wid & 1;

    const int wg  = blockIdx.x;
    const int swz = (wg & 7) * 128 + (wg >> 3);
    const int b   = swz >> 4;
    const int tt  = swz & 15;
    const int m0  = (tt >> 2) * 128;
    const int n0  = (tt & 3) * 128;

    const f16* Pb = P + (size_t)b * pstr;
    const f16* Qb = Qt + (size_t)b * qstr;

    const int srow = tid >> 3;
    const int sswz = (tid & 7) ^ (srow & 7);

    const int fr  = lane & 15;
    const int fs  = lane >> 4;
    const int fx  = fr & 7;

    auto stage = [&](const f16* __restrict__ Gb, int row0, f16* lds, int k0) {
        #pragma unroll
        for (int r = 0; r < 4; ++r) {
            const f16* src = Gb + (size_t)(row0 + r * 32 + srow) * 512 + k0 + sswz * 8;
            gload_lds16(src, lds + r * 2048 + tid * 8);
        }
    };

    f32x4 acc[4][4] = {};

    stage(Pb, m0, &Plds[0][0], 0);
    stage(Qb, n0, &Qlds[0][0], 0);

    // inline r-finish for this block's 128-row slice (RM: m-slice, RN: n-slice)
    if ((RM || RN) && tid < 128) {
        const float* p = part + (size_t)b * 4096 + (RM ? m0 : n0) + tid;
        float s = 0.f;
        #pragma unroll
        for (int jt = 0; jt < 8; ++jt) s += p[jt * 512];
        rs_lds[tid] = (s > 0.f) ? rsqrtf(s) : 0.f;
    }

    for (int t = 0; t < 8; ++t) {
        const int nb = t & 1;
        if (t < 7) {
            stage(Pb, m0, &Plds[nb ^ 1][0], (t + 1) * 64);
            stage(Qb, n0, &Qlds[nb ^ 1][0], (t + 1) * 64);
            asm volatile("s_waitcnt vmcnt(8)" ::: "memory");
        } else {
            asm volatile("s_waitcnt vmcnt(0)" ::: "memory");
        }
        __builtin_amdgcn_s_barrier();

        const f16* Pl = &Plds[nb][0];
        const f16* Ql = &Qlds[nb][0];
        #pragma unroll
        for (int krep = 0; krep < 2; ++krep) {
            const int sp = ((fs + krep * 4) ^ fx) * 8;
            f16x8 af[4], bf[4];
            #pragma unroll
            for (int mi = 0; mi < 4; ++mi)
                af[mi] = *(const f16x8*)&Pl[(wm * 64 + mi * 16 + fr) * 64 + sp];
            #pragma unroll
            for (int ni = 0; ni < 4; ++ni)
                bf[ni] = *(const f16x8*)&Ql[(wn * 64 + ni * 16 + fr) * 64 + sp];
            __builtin_amdgcn_s_setprio(1);
            #pragma unroll
            for (int mi = 0; mi < 4; ++mi)
                #pragma unroll
                for (int ni = 0; ni < 4; ++ni)
                    acc[mi][ni] = __builtin_amdgcn_mfma_f32_16x16x32_f16(
                        af[mi], bf[ni], acc[mi][ni], 0, 0, 0);
            __builtin_amdgcn_s_setprio(0);
        }
        asm volatile("s_waitcnt lgkmcnt(0)" ::: "memory");
        __builtin_amdgcn_sched_barrier(0);
        __builtin_amdgcn_s_barrier();
    }

    const int cmb = (lane >> 4) * 4;
    f32x4 rm4[4];
    float rn1[4];
    if (RM) {
        #pragma unroll
        for (int mi = 0; mi < 4; ++mi)
            rm4[mi] = *(const f32x4*)&rs_lds[wm * 64 + mi * 16 + cmb];
    }
    if (RN) {
        #pragma unroll
        for (int ni = 0; ni < 4; ++ni)
            rn1[ni] = rs_lds[wn * 64 + ni * 16 + fr];
    }
    #pragma unroll
    for (int mi = 0; mi < 4; ++mi) {
        #pragma unroll
        for (int ni = 0; ni < 4; ++ni) {
            const int n = n0 + wn * 64 + ni * 16 + fr;
            const int m = m0 + wm * 64 + mi * 16 + cmb;
            float v[4];
            #pragma unroll
            for (int q = 0; q < 4; ++q) {
                float x = acc[mi][ni][q] * iscale;
                if (RM) x *= rm4[mi][q];
                if (RN) x *= rn1[ni];
                if (BIAS) x += bias[m + q];
                if (RELU) x = fmaxf(x, 0.f);
                v[q] = x * oscale;
            }
            if (OUTF32) {
                float* Cb = (float*)Cout + (size_t)b * cstr;
                f32x4 o; o[0] = v[0]; o[1] = v[1]; o[2] = v[2]; o[3] = v[3];
                *(f32x4*)&Cb[(size_t)n * 512 + m] = o;
            } else {
                f16* Cb = (f16*)Cout + (size_t)b * cstr;
                f16x4 o; o[0] = (f16)v[0]; o[1] = (f16)v[1]; o[2] = (f16)v[2]; o[3] = (f16)v[3];
                *(f16x4*)&Cb[(size_t)n * 512 + m] = o;
            }
        }
    }
}

extern "C" void kernel_launch(void* const* d_in, const int* in_sizes, int n_in,
                              void* d_out, int out_size, void* d_ws, size_t ws_size,
                              hipStream_t stream) {
    const float* X0  = (const float*)d_in[0];
    const float* adj = (const float*)d_in[1];
    const float* W1  = (const float*)d_in[2];
    const float* b1  = (const float*)d_in[3];
    const float* W2  = (const float*)d_in[4];
    const float* b2  = (const float*)d_in[5];
    const float* W3  = (const float*)d_in[6];
    const float* b3  = (const float*)d_in[7];

    uint8_t* ws = (uint8_t*)d_ws;
    float* part = (float*)ws;                               // 64*8*512*4 = 1 MiB
    f16* Wt1 = (f16*)(ws + (1 << 20));                      // 3 x 512 KiB
    f16* A_raw = (f16*)(ws + (1 << 20) + (size_t)3 * NN * 2); // 32 MiB (adj^T f16)
    f16* Xa  = A_raw + (size_t)NB * NN;                     // 32 MiB (X / activations)
    f16* S_t = Xa + (size_t)NB * NN;                        // 32 MiB

    k_prep<<<dim3(12480), dim3(256), 0, stream>>>(adj, A_raw, part, W1, W2, W3, Wt1, X0, Xa);

    dim3 gg(1024), gb(256);
    // ledger: Xa holds 256^l * X_l; Wt = 64*W; S' = c_l * r_j * S_l (c1=256, c2=c3=262144).
    // G1: acc=64*S1            -> store 4*r[m]*acc       = 256*r*S1
    gemm_tn_ct<false, false, false, true,  false><<<gg, gb, 0, stream>>>(Xa,  (size_t)NN, Wt1, (size_t)0,  S_t, (size_t)NN, nullptr, part, 4.f, 1.f);
    // G2: acc=256*(A S1)/r_i   -> X1=relu(acc/256*r[n] + b1), store 256*X1
    gemm_tn_ct<true,  true,  false, false, true ><<<gg, gb, 0, stream>>>(S_t, (size_t)NN, A_raw, (size_t)NN, Xa, (size_t)NN, b1, part, 1.f / 256.f, 256.f);
    // G3: acc=16384*S2         -> store 16*r[m]*acc      = 262144*r*S2
    gemm_tn_ct<false, false, false, true,  false><<<gg, gb, 0, stream>>>(Xa,  (size_t)NN, Wt1 + NN, (size_t)0,  S_t, (size_t)NN, nullptr, part, 16.f, 1.f);
    // G4: acc=262144*(A S2)/r_i -> X2=relu(acc/262144*r[n] + b2), store 256*X2
    gemm_tn_ct<true,  true,  false, false, true ><<<gg, gb, 0, stream>>>(S_t, (size_t)NN, A_raw, (size_t)NN, Xa, (size_t)NN, b2, part, 1.f / 262144.f, 256.f);
    // G5: acc=16384*S3         -> store 16*r[m]*acc
    gemm_tn_ct<false, false, false, true,  false><<<gg, gb, 0, stream>>>(Xa,  (size_t)NN, Wt1 + 2 * NN, (size_t)0,  S_t, (size_t)NN, nullptr, part, 16.f, 1.f);
    // G6: out = acc/262144*r[n] + b3  (f32)
    gemm_tn_ct<true,  false, true,  false, true ><<<gg, gb, 0, stream>>>(S_t, (size_t)NN, A_raw, (size_t)NN, d_out, (size_t)NN, b3, part, 1.f / 262144.f, 1.f);
}